// Round 14
// baseline (903.421 us; speedup 1.0000x reference)
//
#include <hip/hip_runtime.h>
#include <math.h>

// ============================================================================
// RPN pipeline for MI355X.
// L0: H=W=32, stride 8, scale 4096 ; L1: H=W=16, stride 16, scale 16384
// A=3 ratios {0.5,1,2}. N0=3072, N1=768 anchors/batch. BS=4.
// Numeric recipe (validated bitwise R1-R13, absmax 0.0): fp64 accumulation for
// every sum feeding the score/box path, fp32 rounding at layer boundaries.
// R14: conv occupancy push. 1280 blocks (5/CU) -> 2048 (8/CU = HW max):
// L0 KS=6 (1536 blk, 24 ktiles), L1 KS=8 (512 blk, 18 ktiles).
// __launch_bounds__(256,8) pins VGPR<=64 (current 52; spill tripwire =
// WRITE_SIZE per R6). rhd reduce loops -> 6/8 partials (fp64 regroup exact).
// ============================================================================

// ---------------- merged conv3x3 implicit GEMM, split-K, fp32 LDS -----------
__global__ __launch_bounds__(256, 8) void conv3_sk_u(
    const float* __restrict__ feat0, const float* __restrict__ feat1,
    const float* __restrict__ conv_w,
    double* __restrict__ part0, double* __restrict__ part1)
{
  __shared__ float Ald[2][16][64];
  __shared__ float Bld[2][16][64];
  const int t = threadIdx.x;
  const int bid = blockIdx.x;
  const float* feat;
  double* part;
  int oc_t, p_t, k_base, ktiles, hw_sh, w_sh, H;
  if (bid < 1536) {                       // L0: 6 k-chunks x 4 oc x 64 p
    int kc = bid >> 8;                    // 0..5
    int r = bid & 255;
    feat = feat0; part = part0 + (size_t)kc * 4096 * 256;
    oc_t = r & 3; p_t = (r >> 2) & 63;
    k_base = kc * 384; ktiles = 24; hw_sh = 10; w_sh = 5; H = 32;
  } else {                                // L1: 8 k-chunks x 4 oc x 16 p
    int b2 = bid - 1536;
    int kc = b2 >> 6;                     // 0..7
    int r = b2 & 63;
    feat = feat1; part = part1 + (size_t)kc * 1024 * 256;
    oc_t = r & 3; p_t = (r >> 2) & 15;
    k_base = kc * 288; ktiles = 18; hw_sh = 8; w_sh = 4; H = 16;
  }
  const int oc_base = oc_t * 64;
  const int p_base  = p_t * 64;
  const int wmask = H - 1, hwmask = (1 << hw_sh) - 1;
  const int skk = t >> 4;
  const int q4  = (t & 15) * 4;

  float a_r[4], b_r[4];
  auto load_tile = [&](int kt) {
    const int k0 = k_base + kt * 16;
    const float* wrow = conv_w + (size_t)(oc_base + q4) * 2304 + (k0 + skk);
#pragma unroll
    for (int u = 0; u < 4; ++u) a_r[u] = wrow[(size_t)u * 2304];
    int p = p_base + q4;
    int b = p >> hw_sh, pin = p & hwmask;
    int y = pin >> w_sh, x0 = pin & wmask;
    int k = k0 + skk;
    int ic = k / 9, rr = k - ic * 9;
    int ky = rr / 3, kx = rr - ky * 3;
    int iy = y + ky - 1;
    const float* frow = feat + (((b << 8) + ic) << hw_sh) + (iy << w_sh);
    bool yok = (unsigned)iy < (unsigned)H;
#pragma unroll
    for (int u = 0; u < 4; ++u) {
      int ix = x0 + u + kx - 1;
      b_r[u] = (yok && (unsigned)ix < (unsigned)H) ? frow[ix] : 0.f;
    }
  };

  const int ty4 = (t >> 4) * 4;
  const int tx4 = (t & 15) * 4;
  double acc[4][4] = {};

  load_tile(0);
  for (int kt = 0; kt < ktiles; ++kt) {
    const int buf = kt & 1;
    *(float4*)&Ald[buf][skk][q4] = make_float4(a_r[0], a_r[1], a_r[2], a_r[3]);
    *(float4*)&Bld[buf][skk][q4] = make_float4(b_r[0], b_r[1], b_r[2], b_r[3]);
    __syncthreads();
    if (kt + 1 < ktiles) load_tile(kt + 1);
#pragma unroll
    for (int kk = 0; kk < 16; ++kk) {
      float4 av = *(const float4*)&Ald[buf][kk][ty4];
      float4 bv = *(const float4*)&Bld[buf][kk][tx4];
      double ad[4] = {(double)av.x, (double)av.y, (double)av.z, (double)av.w};
      double bd[4] = {(double)bv.x, (double)bv.y, (double)bv.z, (double)bv.w};
#pragma unroll
      for (int i = 0; i < 4; ++i)
#pragma unroll
        for (int j = 0; j < 4; ++j) acc[i][j] += ad[i] * bd[j];
    }
  }
#pragma unroll
  for (int j = 0; j < 4; ++j) {
    int p = p_base + tx4 + j;
    double* row = part + (size_t)p * 256 + oc_base + ty4;
    *(double2*)&row[0] = make_double2(acc[0][j], acc[1][j]);
    *(double2*)&row[2] = make_double2(acc[2][j], acc[3][j]);
  }
}

// ---------------- fused reduce(KS=6/8)+bias+ReLU + 1x1 heads + decode -------
__global__ __launch_bounds__(256) void rhd_k(
    const double* __restrict__ part0, const double* __restrict__ part1,
    const float* __restrict__ conv_b,
    const float* __restrict__ cls_w, const float* __restrict__ cls_b,
    const float* __restrict__ reg_w, const float* __restrict__ reg_b,
    float* __restrict__ box0, float* __restrict__ sc0,
    float* __restrict__ box1, float* __restrict__ sc1)
{
  int wid = (blockIdx.x * 256 + threadIdx.x) >> 6;
  int lane = threadIdx.x & 63;
  int lvl = wid >= 4096;
  const double* part = lvl ? part1 : part0;
  int p = lvl ? wid - 4096 : wid;
  int M = lvl ? 1024 : 4096;
  int KS = lvl ? 8 : 6;
  double s4[4];
  {
    float4 bv = ((const float4*)conv_b)[lane];
    s4[0] = (double)bv.x; s4[1] = (double)bv.y;
    s4[2] = (double)bv.z; s4[3] = (double)bv.w;
  }
  for (int ks = 0; ks < KS; ++ks) {
    const double2* pr = (const double2*)(part + (size_t)ks * M * 256 + (size_t)p * 256);
    double2 a = pr[2 * lane], b = pr[2 * lane + 1];
    s4[0] += a.x; s4[1] += a.y; s4[2] += b.x; s4[3] += b.y;
  }
  float xv[4];
#pragma unroll
  for (int q = 0; q < 4; ++q) {
    float f = (float)s4[q];
    xv[q] = f > 0.f ? f : 0.f;
  }
  double acc[15];
#pragma unroll
  for (int o = 0; o < 15; ++o) {
    const float* wr = (o < 3) ? (cls_w + o * 256) : (reg_w + (o - 3) * 256);
    float4 wv = ((const float4*)wr)[lane];
    acc[o] = (double)wv.x * (double)xv[0] + (double)wv.y * (double)xv[1] +
             (double)wv.z * (double)xv[2] + (double)wv.w * (double)xv[3];
  }
#pragma unroll
  for (int d = 1; d < 64; d <<= 1)
#pragma unroll
    for (int o = 0; o < 15; ++o)
      acc[o] += __shfl_xor(acc[o], d, 64);
  if (lane < 3) {
    int a = lane;
    float cls = (float)(acc[a] + (double)cls_b[a]);
    float score = 1.f / (1.f + expf(-cls));
    float dx = (float)(acc[3 + a * 4 + 0] + (double)reg_b[a * 4 + 0]);
    float dy = (float)(acc[3 + a * 4 + 1] + (double)reg_b[a * 4 + 1]);
    float dw = (float)(acc[3 + a * 4 + 2] + (double)reg_b[a * 4 + 2]);
    float dh = (float)(acc[3 + a * 4 + 3] + (double)reg_b[a * 4 + 3]);
    int hw_sh = lvl ? 8 : 10, w_sh = lvl ? 4 : 5, Wd = lvl ? 16 : 32;
    float S = lvl ? 16.f : 8.f;
    double scale = lvl ? 16384.0 : 4096.0;
    int b = p >> hw_sh, pin = p & ((1 << hw_sh) - 1);
    int y = pin >> w_sh, x = pin & (Wd - 1);
    double ratio = (a == 0) ? 0.5 : (a == 1 ? 1.0 : 2.0);
    float w_a = (float)sqrt(scale / ratio);
    float h_a = (float)sqrt(scale * ratio);
    float cx = ((float)x + 0.5f) * S;
    float cy = ((float)y + 0.5f) * S;
    float x1 = cx - 0.5f * w_a, y1 = cy - 0.5f * h_a;
    float x2 = cx + 0.5f * w_a, y2 = cy + 0.5f * h_a;
    x1 = fminf(fmaxf(x1, 0.f), 256.f); y1 = fminf(fmaxf(y1, 0.f), 256.f);
    x2 = fminf(fmaxf(x2, 0.f), 256.f); y2 = fminf(fmaxf(y2, 0.f), 256.f);
    float wa = x2 - x1, ha = y2 - y1;
    float cxa = x1 + 0.5f * wa, cya = y1 + 0.5f * ha;
    float ncx = dx * wa + cxa;
    float ncy = dy * ha + cya;
    float nw = expf(dw) * wa;
    float nh = expf(dh) * ha;
    float bx1 = ncx - 0.5f * nw, by1 = ncy - 0.5f * nh;
    float bx2 = ncx + 0.5f * nw, by2 = ncy + 0.5f * nh;
    bx1 = fminf(fmaxf(bx1, 0.f), 256.f); by1 = fminf(fmaxf(by1, 0.f), 256.f);
    bx2 = fminf(fmaxf(bx2, 0.f), 256.f); by2 = fminf(fmaxf(by2, 0.f), 256.f);
    int n = pin * 3 + a;
    if (lvl) {
      ((float4*)box1)[(size_t)b * 768 + n] = make_float4(bx1, by1, bx2, by2);
      sc1[b * 768 + n] = score;
    } else {
      ((float4*)box0)[(size_t)b * 3072 + n] = make_float4(bx1, by1, bx2, by2);
      sc0[b * 3072 + n] = score;
    }
  }
}

// ---------------- stable descending enumeration sort, both levels -----------
__global__ __launch_bounds__(256) void sort_level_k(
    const float* __restrict__ sc0, const float* __restrict__ box0,
    float* __restrict__ ssc0, float* __restrict__ sbox0,
    const float* __restrict__ sc1, const float* __restrict__ box1,
    float* __restrict__ ssc1, float* __restrict__ sbox1)
{
  __shared__ __align__(16) float s[3072];
  int z = blockIdx.x;
  const float *sc, *box; float *ssc, *sbox; int N, b, c;
  if (z < 48) { sc = sc0; box = box0; ssc = ssc0; sbox = sbox0; N = 3072; b = z / 12; c = z % 12; }
  else { int z2 = z - 48; sc = sc1; box = box1; ssc = ssc1; sbox = sbox1; N = 768; b = z2 / 3; c = z2 % 3; }
  const float* scb = sc + (size_t)b * N;
  for (int j = threadIdx.x; j < N; j += 256) s[j] = scb[j];
  __syncthreads();
  int i = c * 256 + threadIdx.x;
  float si = s[i];
  int rank = 0;
  const float4* sv = (const float4*)s;
  for (int j4 = 0; j4 < (N >> 2); ++j4) {
    float4 v = sv[j4];
    int j = j4 * 4;
    rank += (v.x > si) || (v.x == si && (j + 0) < i);
    rank += (v.y > si) || (v.y == si && (j + 1) < i);
    rank += (v.z > si) || (v.z == si && (j + 2) < i);
    rank += (v.w > si) || (v.w == si && (j + 3) < i);
  }
  ssc[(size_t)b * N + rank] = si;
  float4 bi = ((const float4*)box)[(size_t)b * N + i];
  ((float4*)sbox)[(size_t)b * N + rank] = bi;
}

// ---------------- NMS bitmask + transposed diagonal tiles, one kernel -------
__global__ __launch_bounds__(256) void mask_col_k(
    const float* __restrict__ sbox0, const float* __restrict__ sbox1,
    unsigned long long* __restrict__ mask0, unsigned long long* __restrict__ mask1,
    unsigned long long* __restrict__ colD0, unsigned long long* __restrict__ colD1)
{
  int bid = blockIdx.x;
  if (bid < 2448) {
    __shared__ float4 bj[64];
    const float* sbox; unsigned long long* mask; int N, words, w, i_ch, b;
    if (bid < 2304) {
      sbox = sbox0; mask = mask0; N = 3072; words = 48;
      w = bid % 48; int r = bid / 48; i_ch = r % 12; b = r / 12;
    } else {
      int z = bid - 2304;
      sbox = sbox1; mask = mask1; N = 768; words = 12;
      w = z % 12; int r = z / 12; i_ch = r % 3; b = r / 3;
    }
    int i = i_ch * 256 + threadIdx.x;
    if (threadIdx.x < 64)
      bj[threadIdx.x] = ((const float4*)sbox)[(size_t)b * N + w * 64 + threadIdx.x];
    __syncthreads();
    float4 bi = ((const float4*)sbox)[(size_t)b * N + i];
    float ai = (bi.z - bi.x) * (bi.w - bi.y);
    unsigned long long m = 0ull;
#pragma unroll 16
    for (int jj = 0; jj < 64; ++jj) {
      int j = w * 64 + jj;
      float4 bv = bj[jj];
      float lx = fmaxf(bi.x, bv.x), ly = fmaxf(bi.y, bv.y);
      float rx = fminf(bi.z, bv.z), ry = fminf(bi.w, bv.w);
      float iw = fmaxf(rx - lx, 0.f), ih = fmaxf(ry - ly, 0.f);
      float inter = iw * ih;
      float aj = (bv.z - bv.x) * (bv.w - bv.y);
      float iou = inter / (ai + aj - inter);   // NaN compares false, matches jnp
      if ((iou > 0.7f) & (j > i)) m |= (1ull << jj);
    }
    mask[((size_t)b * N + i) * words + w] = m;
  } else {
    __shared__ float4 tb[4][64];
    int sub = threadIdx.x >> 6, lane = threadIdx.x & 63;
    const float* sbox; unsigned long long* colD; int N, tile, b;
    if (bid < 2496) {
      int unit = (bid - 2448) * 4 + sub;
      sbox = sbox0; colD = colD0; N = 3072;
      tile = unit % 48; b = unit / 48;
    } else {
      int unit = (bid - 2496) * 4 + sub;
      sbox = sbox1; colD = colD1; N = 768;
      tile = unit % 12; b = unit / 12;
    }
    tb[sub][lane] = ((const float4*)sbox)[(size_t)b * N + tile * 64 + lane];
    __syncthreads();
    float4 bq = tb[sub][lane];
    float aq = (bq.z - bq.x) * (bq.w - bq.y);
    unsigned long long col = 0ull;
#pragma unroll 16
    for (int ii = 0; ii < 64; ++ii) {
      float4 bi = tb[sub][ii];
      float lx = fmaxf(bq.x, bi.x), ly = fmaxf(bq.y, bi.y);
      float rx = fminf(bq.z, bi.z), ry = fminf(bq.w, bi.w);
      float iw = fmaxf(rx - lx, 0.f), ih = fmaxf(ry - ly, 0.f);
      float inter = iw * ih;
      float ai = (bi.z - bi.x) * (bi.w - bi.y);
      float iou = inter / (aq + ai - inter);
      if ((iou > 0.7f) & (lane > ii)) col |= (1ull << ii);
    }
    colD[(size_t)b * N + tile * 64 + lane] = col;
  }
}

// ---------------- exact greedy scan v3: 4-wave propagation per (b,lvl) ------
__global__ __launch_bounds__(256) void nms_scan_k(
    const float* __restrict__ ssc0, const float* __restrict__ sbox0,
    const unsigned long long* __restrict__ mask0,
    const unsigned long long* __restrict__ colD0,
    const float* __restrict__ ssc1, const float* __restrict__ sbox1,
    const unsigned long long* __restrict__ mask1,
    const unsigned long long* __restrict__ colD1,
    float* __restrict__ cb, float* __restrict__ cs)
{
  int z = blockIdx.x;
  int lvl = z >> 2, b = z & 3;
  int N = lvl ? 768 : 3072;
  int words = lvl ? 12 : 48;
  const float* ssc = (lvl ? ssc1 : ssc0) + (size_t)b * N;
  const float4* sbox = ((const float4*)(lvl ? sbox1 : sbox0)) + (size_t)b * N;
  const unsigned long long* mask = (lvl ? mask1 : mask0) + (size_t)b * N * words;
  const unsigned long long* colD = (lvl ? colD1 : colD0) + (size_t)b * N;
  const int tid = threadIdx.x;
  const int lane = tid & 63;
  const int wv = tid >> 6;
  float* csb = cs + (size_t)b * 2000 + lvl * 1000;
  float4* cbb = (float4*)(cb + ((size_t)b * 2000 + lvl * 1000) * 4);

  __shared__ unsigned long long rem[48];
  __shared__ unsigned long long part[4][64];   // extent 64 (R13 OOB fix)
  __shared__ unsigned long long keepSh;
  __shared__ int doneSh;

  if (tid < 48) rem[tid] = 0ull;
  if (tid == 0) doneSh = 0;
  for (int q = tid; q < 1000; q += 256) {
    csb[q] = -1.f;
    cbb[q] = make_float4(-1.f, -1.f, -1.f, -1.f);
  }
  unsigned long long colv = 0ull; float sc_i = 0.f; float4 bx_i;
  if (wv == 0) { colv = colD[lane]; sc_i = ssc[lane]; bx_i = sbox[lane]; }
  int kept_base = 0;
  __syncthreads();

  for (int t = 0; t < words; ++t) {
    unsigned long long v[16];
    if (lane < words) {
      const unsigned long long* rowb =
          mask + ((size_t)t * 64 + wv * 16) * words + lane;
#pragma unroll
      for (int s = 0; s < 16; ++s) v[s] = rowb[(size_t)s * words];
    }
    if (wv == 0) {
      unsigned long long wr = rem[t];
      bool rm = (wr >> lane) & 1ull;
      bool kp = false;
      unsigned long long Rv = wr;
      unsigned long long Kv = 0ull;
      while (true) {
        bool F = (!rm) && (!kp) && ((colv & ~Rv) == 0ull);
        unsigned long long Fv = __ballot(F);
        if (Fv == 0ull) break;
        kp = kp || F;
        Kv |= Fv;
        bool newr = (!rm) && (!kp) && ((colv & Fv) != 0ull);
        rm = rm || newr;
        Rv = __ballot(rm);
      }
      if (kp) {
        int rank = kept_base + __popcll(Kv & ((1ull << lane) - 1ull));
        if (rank < 1000) { csb[rank] = sc_i; cbb[rank] = bx_i; }
      }
      kept_base += __popcll(Kv);
      if (lane == 0) {
        keepSh = Kv;
        doneSh = (kept_base >= 1000 || t + 1 >= words) ? 1 : 0;
      }
      if (t + 1 < words) {
        int i2 = (t + 1) * 64 + lane;
        colv = colD[i2]; sc_i = ssc[i2]; bx_i = sbox[i2];
      }
    }
    __syncthreads();
    unsigned long long k64 = keepSh;
    int done = doneSh;
    if (lane < words) {
      unsigned long long acc = 0ull;
#pragma unroll
      for (int s = 0; s < 16; ++s)
        acc |= (((k64 >> (wv * 16 + s)) & 1ull) ? v[s] : 0ull);
      part[wv][lane] = acc;
    }
    __syncthreads();
    if (done) break;
    if (tid > t && tid < words)
      rem[tid] |= part[0][tid] | part[1][tid] | part[2][tid] | part[3][tid];
    __syncthreads();
  }
}

// ---------------- final stable descending sort of 2000, gather boxes --------
__global__ __launch_bounds__(256) void final_sort_k(
    const float* __restrict__ cs, const float* __restrict__ cb,
    float* __restrict__ out)
{
  __shared__ __align__(16) float s[2000];
  int b = blockIdx.x >> 3, c = blockIdx.x & 7;
  const float* csb = cs + (size_t)b * 2000;
  for (int j = threadIdx.x; j < 2000; j += 256) s[j] = csb[j];
  __syncthreads();
  if (threadIdx.x >= 250) return;
  int li = c * 250 + threadIdx.x;
  float si = s[li];
  int rank = 0;
  const float4* sv = (const float4*)s;
  for (int j4 = 0; j4 < 500; ++j4) {
    float4 v = sv[j4];
    int j = j4 * 4;
    rank += (v.x > si) || (v.x == si && (j + 0) < li);
    rank += (v.y > si) || (v.y == si && (j + 1) < li);
    rank += (v.z > si) || (v.z == si && (j + 2) < li);
    rank += (v.w > si) || (v.w == si && (j + 3) < li);
  }
  float4 bi = ((const float4*)cb)[(size_t)b * 2000 + li];
  ((float4*)out)[(size_t)b * 2000 + rank] = bi;
}

// ============================================================================
extern "C" void kernel_launch(void* const* d_in, const int* in_sizes, int n_in,
                              void* d_out, int out_size, void* d_ws, size_t ws_size,
                              hipStream_t stream) {
  const float* feat0  = (const float*)d_in[0];
  const float* feat1  = (const float*)d_in[1];
  const float* conv_w = (const float*)d_in[2];
  const float* conv_b = (const float*)d_in[3];
  const float* cls_w  = (const float*)d_in[4];
  const float* cls_b  = (const float*)d_in[5];
  const float* reg_w  = (const float*)d_in[6];
  const float* reg_b  = (const float*)d_in[7];

  char* p = (char*)d_ws;
  auto alloc = [&](size_t bytes) {
    char* r = p;
    p += (bytes + 255) & ~(size_t)255;
    return r;
  };
  double* part0 = (double*)alloc((size_t)6 * 4096 * 256 * 8);    // 50.3 MB
  double* part1 = (double*)alloc((size_t)8 * 1024 * 256 * 8);    // 16.8 MB
  float* box0 = (float*)alloc((size_t)4 * 3072 * 16);
  float* sc0  = (float*)alloc((size_t)4 * 3072 * 4);
  float* box1 = (float*)alloc((size_t)4 * 768 * 16);
  float* sc1  = (float*)alloc((size_t)4 * 768 * 4);
  float* sbox0 = (float*)alloc((size_t)4 * 3072 * 16);
  float* ssc0  = (float*)alloc((size_t)4 * 3072 * 4);
  float* sbox1 = (float*)alloc((size_t)4 * 768 * 16);
  float* ssc1  = (float*)alloc((size_t)4 * 768 * 4);
  unsigned long long* mask0 = (unsigned long long*)alloc((size_t)4 * 3072 * 48 * 8);
  unsigned long long* mask1 = (unsigned long long*)alloc((size_t)4 * 768 * 12 * 8);
  unsigned long long* colD0 = (unsigned long long*)alloc((size_t)4 * 3072 * 8);
  unsigned long long* colD1 = (unsigned long long*)alloc((size_t)4 * 768 * 8);
  float* cb = (float*)alloc((size_t)4 * 2000 * 16);
  float* cs = (float*)alloc((size_t)4 * 2000 * 4);

  conv3_sk_u<<<2048, 256, 0, stream>>>(feat0, feat1, conv_w, part0, part1);
  rhd_k<<<1280, 256, 0, stream>>>(part0, part1, conv_b, cls_w, cls_b,
                                  reg_w, reg_b, box0, sc0, box1, sc1);
  sort_level_k<<<60, 256, 0, stream>>>(sc0, box0, ssc0, sbox0,
                                       sc1, box1, ssc1, sbox1);
  mask_col_k<<<2508, 256, 0, stream>>>(sbox0, sbox1, mask0, mask1, colD0, colD1);
  nms_scan_k<<<8, 256, 0, stream>>>(ssc0, sbox0, mask0, colD0,
                                    ssc1, sbox1, mask1, colD1, cb, cs);
  final_sort_k<<<32, 256, 0, stream>>>(cs, cb, (float*)d_out);
}

// Round 15
// 492.408 us; speedup vs baseline: 1.8347x; 1.8347x over previous
//
#include <hip/hip_runtime.h>
#include <math.h>

// ============================================================================
// RPN pipeline for MI355X.
// L0: H=W=32, stride 8, scale 4096 ; L1: H=W=16, stride 16, scale 16384
// A=3 ratios {0.5,1,2}. N0=3072, N1=768 anchors/batch. BS=4.
// Numeric recipe (validated bitwise R1-R13, absmax 0.0): fp64 accumulation for
// every sum feeding the score/box path, fp32 rounding at layer boundaries.
// R15: revert R14 ((256,8) capped VGPR at 64 < the kernel's ~100-reg need ->
// acc spilled in-loop: WRITE 645MB, conv 608us — R6's failure mode repeated).
// Restored R13 config: conv 1280 blocks KS=4/4, (256,4)=128-VGPR budget
// (kernel's operating point; 5 blocks/CU is the occupancy ceiling for this
// register footprint). Conv busy-time ~145us vs ~115us fp64-FMA issue floor.
// ============================================================================

// ---------------- merged conv3x3 implicit GEMM, split-K, fp32 LDS -----------
__global__ __launch_bounds__(256, 4) void conv3_sk_u(
    const float* __restrict__ feat0, const float* __restrict__ feat1,
    const float* __restrict__ conv_w,
    double* __restrict__ part0, double* __restrict__ part1)
{
  __shared__ float Ald[2][16][64];
  __shared__ float Bld[2][16][64];
  const int t = threadIdx.x;
  const int bid = blockIdx.x;
  const float* feat;
  double* part;
  int oc_t, p_t, k_base, hw_sh, w_sh, H;
  if (bid < 1024) {
    int kc = bid >> 8;
    feat = feat0; part = part0 + (size_t)kc * 4096 * 256;
    oc_t = bid & 3; p_t = (bid >> 2) & 63;
    k_base = kc * 576; hw_sh = 10; w_sh = 5; H = 32;
  } else {
    int b2 = bid - 1024;
    int kc = b2 >> 6;
    feat = feat1; part = part1 + (size_t)kc * 1024 * 256;
    oc_t = b2 & 3; p_t = (b2 >> 2) & 15;
    k_base = kc * 576; hw_sh = 8; w_sh = 4; H = 16;
  }
  const int oc_base = oc_t * 64;
  const int p_base  = p_t * 64;
  const int wmask = H - 1, hwmask = (1 << hw_sh) - 1;
  const int skk = t >> 4;
  const int q4  = (t & 15) * 4;

  float a_r[4], b_r[4];
  auto load_tile = [&](int kt) {
    const int k0 = k_base + kt * 16;
    const float* wrow = conv_w + (size_t)(oc_base + q4) * 2304 + (k0 + skk);
#pragma unroll
    for (int u = 0; u < 4; ++u) a_r[u] = wrow[(size_t)u * 2304];
    int p = p_base + q4;
    int b = p >> hw_sh, pin = p & hwmask;
    int y = pin >> w_sh, x0 = pin & wmask;
    int k = k0 + skk;
    int ic = k / 9, rr = k - ic * 9;
    int ky = rr / 3, kx = rr - ky * 3;
    int iy = y + ky - 1;
    const float* frow = feat + (((b << 8) + ic) << hw_sh) + (iy << w_sh);
    bool yok = (unsigned)iy < (unsigned)H;
#pragma unroll
    for (int u = 0; u < 4; ++u) {
      int ix = x0 + u + kx - 1;
      b_r[u] = (yok && (unsigned)ix < (unsigned)H) ? frow[ix] : 0.f;
    }
  };

  const int ty4 = (t >> 4) * 4;
  const int tx4 = (t & 15) * 4;
  double acc[4][4] = {};

  load_tile(0);
  for (int kt = 0; kt < 36; ++kt) {
    const int buf = kt & 1;
    *(float4*)&Ald[buf][skk][q4] = make_float4(a_r[0], a_r[1], a_r[2], a_r[3]);
    *(float4*)&Bld[buf][skk][q4] = make_float4(b_r[0], b_r[1], b_r[2], b_r[3]);
    __syncthreads();
    if (kt + 1 < 36) load_tile(kt + 1);
#pragma unroll
    for (int kk = 0; kk < 16; ++kk) {
      float4 av = *(const float4*)&Ald[buf][kk][ty4];
      float4 bv = *(const float4*)&Bld[buf][kk][tx4];
      double ad[4] = {(double)av.x, (double)av.y, (double)av.z, (double)av.w};
      double bd[4] = {(double)bv.x, (double)bv.y, (double)bv.z, (double)bv.w};
#pragma unroll
      for (int i = 0; i < 4; ++i)
#pragma unroll
        for (int j = 0; j < 4; ++j) acc[i][j] += ad[i] * bd[j];
    }
  }
#pragma unroll
  for (int j = 0; j < 4; ++j) {
    int p = p_base + tx4 + j;
    double* row = part + (size_t)p * 256 + oc_base + ty4;
    *(double2*)&row[0] = make_double2(acc[0][j], acc[1][j]);
    *(double2*)&row[2] = make_double2(acc[2][j], acc[3][j]);
  }
}

// ---------------- fused reduce(KS=4)+bias+ReLU + 1x1 heads + decode ---------
__global__ __launch_bounds__(256) void rhd_k(
    const double* __restrict__ part0, const double* __restrict__ part1,
    const float* __restrict__ conv_b,
    const float* __restrict__ cls_w, const float* __restrict__ cls_b,
    const float* __restrict__ reg_w, const float* __restrict__ reg_b,
    float* __restrict__ box0, float* __restrict__ sc0,
    float* __restrict__ box1, float* __restrict__ sc1)
{
  int wid = (blockIdx.x * 256 + threadIdx.x) >> 6;
  int lane = threadIdx.x & 63;
  int lvl = wid >= 4096;
  const double* part = lvl ? part1 : part0;
  int p = lvl ? wid - 4096 : wid;
  int M = lvl ? 1024 : 4096;
  double s4[4];
  {
    float4 bv = ((const float4*)conv_b)[lane];
    s4[0] = (double)bv.x; s4[1] = (double)bv.y;
    s4[2] = (double)bv.z; s4[3] = (double)bv.w;
  }
#pragma unroll
  for (int ks = 0; ks < 4; ++ks) {
    const double2* pr = (const double2*)(part + (size_t)ks * M * 256 + (size_t)p * 256);
    double2 a = pr[2 * lane], b = pr[2 * lane + 1];
    s4[0] += a.x; s4[1] += a.y; s4[2] += b.x; s4[3] += b.y;
  }
  float xv[4];
#pragma unroll
  for (int q = 0; q < 4; ++q) {
    float f = (float)s4[q];
    xv[q] = f > 0.f ? f : 0.f;
  }
  double acc[15];
#pragma unroll
  for (int o = 0; o < 15; ++o) {
    const float* wr = (o < 3) ? (cls_w + o * 256) : (reg_w + (o - 3) * 256);
    float4 wv = ((const float4*)wr)[lane];
    acc[o] = (double)wv.x * (double)xv[0] + (double)wv.y * (double)xv[1] +
             (double)wv.z * (double)xv[2] + (double)wv.w * (double)xv[3];
  }
#pragma unroll
  for (int d = 1; d < 64; d <<= 1)
#pragma unroll
    for (int o = 0; o < 15; ++o)
      acc[o] += __shfl_xor(acc[o], d, 64);
  if (lane < 3) {
    int a = lane;
    float cls = (float)(acc[a] + (double)cls_b[a]);
    float score = 1.f / (1.f + expf(-cls));
    float dx = (float)(acc[3 + a * 4 + 0] + (double)reg_b[a * 4 + 0]);
    float dy = (float)(acc[3 + a * 4 + 1] + (double)reg_b[a * 4 + 1]);
    float dw = (float)(acc[3 + a * 4 + 2] + (double)reg_b[a * 4 + 2]);
    float dh = (float)(acc[3 + a * 4 + 3] + (double)reg_b[a * 4 + 3]);
    int hw_sh = lvl ? 8 : 10, w_sh = lvl ? 4 : 5, Wd = lvl ? 16 : 32;
    float S = lvl ? 16.f : 8.f;
    double scale = lvl ? 16384.0 : 4096.0;
    int b = p >> hw_sh, pin = p & ((1 << hw_sh) - 1);
    int y = pin >> w_sh, x = pin & (Wd - 1);
    double ratio = (a == 0) ? 0.5 : (a == 1 ? 1.0 : 2.0);
    float w_a = (float)sqrt(scale / ratio);
    float h_a = (float)sqrt(scale * ratio);
    float cx = ((float)x + 0.5f) * S;
    float cy = ((float)y + 0.5f) * S;
    float x1 = cx - 0.5f * w_a, y1 = cy - 0.5f * h_a;
    float x2 = cx + 0.5f * w_a, y2 = cy + 0.5f * h_a;
    x1 = fminf(fmaxf(x1, 0.f), 256.f); y1 = fminf(fmaxf(y1, 0.f), 256.f);
    x2 = fminf(fmaxf(x2, 0.f), 256.f); y2 = fminf(fmaxf(y2, 0.f), 256.f);
    float wa = x2 - x1, ha = y2 - y1;
    float cxa = x1 + 0.5f * wa, cya = y1 + 0.5f * ha;
    float ncx = dx * wa + cxa;
    float ncy = dy * ha + cya;
    float nw = expf(dw) * wa;
    float nh = expf(dh) * ha;
    float bx1 = ncx - 0.5f * nw, by1 = ncy - 0.5f * nh;
    float bx2 = ncx + 0.5f * nw, by2 = ncy + 0.5f * nh;
    bx1 = fminf(fmaxf(bx1, 0.f), 256.f); by1 = fminf(fmaxf(by1, 0.f), 256.f);
    bx2 = fminf(fmaxf(bx2, 0.f), 256.f); by2 = fminf(fmaxf(by2, 0.f), 256.f);
    int n = pin * 3 + a;
    if (lvl) {
      ((float4*)box1)[(size_t)b * 768 + n] = make_float4(bx1, by1, bx2, by2);
      sc1[b * 768 + n] = score;
    } else {
      ((float4*)box0)[(size_t)b * 3072 + n] = make_float4(bx1, by1, bx2, by2);
      sc0[b * 3072 + n] = score;
    }
  }
}

// ---------------- stable descending enumeration sort, both levels -----------
__global__ __launch_bounds__(256) void sort_level_k(
    const float* __restrict__ sc0, const float* __restrict__ box0,
    float* __restrict__ ssc0, float* __restrict__ sbox0,
    const float* __restrict__ sc1, const float* __restrict__ box1,
    float* __restrict__ ssc1, float* __restrict__ sbox1)
{
  __shared__ __align__(16) float s[3072];
  int z = blockIdx.x;
  const float *sc, *box; float *ssc, *sbox; int N, b, c;
  if (z < 48) { sc = sc0; box = box0; ssc = ssc0; sbox = sbox0; N = 3072; b = z / 12; c = z % 12; }
  else { int z2 = z - 48; sc = sc1; box = box1; ssc = ssc1; sbox = sbox1; N = 768; b = z2 / 3; c = z2 % 3; }
  const float* scb = sc + (size_t)b * N;
  for (int j = threadIdx.x; j < N; j += 256) s[j] = scb[j];
  __syncthreads();
  int i = c * 256 + threadIdx.x;
  float si = s[i];
  int rank = 0;
  const float4* sv = (const float4*)s;
  for (int j4 = 0; j4 < (N >> 2); ++j4) {
    float4 v = sv[j4];
    int j = j4 * 4;
    rank += (v.x > si) || (v.x == si && (j + 0) < i);
    rank += (v.y > si) || (v.y == si && (j + 1) < i);
    rank += (v.z > si) || (v.z == si && (j + 2) < i);
    rank += (v.w > si) || (v.w == si && (j + 3) < i);
  }
  ssc[(size_t)b * N + rank] = si;
  float4 bi = ((const float4*)box)[(size_t)b * N + i];
  ((float4*)sbox)[(size_t)b * N + rank] = bi;
}

// ---------------- NMS bitmask + transposed diagonal tiles, one kernel -------
__global__ __launch_bounds__(256) void mask_col_k(
    const float* __restrict__ sbox0, const float* __restrict__ sbox1,
    unsigned long long* __restrict__ mask0, unsigned long long* __restrict__ mask1,
    unsigned long long* __restrict__ colD0, unsigned long long* __restrict__ colD1)
{
  int bid = blockIdx.x;
  if (bid < 2448) {
    __shared__ float4 bj[64];
    const float* sbox; unsigned long long* mask; int N, words, w, i_ch, b;
    if (bid < 2304) {
      sbox = sbox0; mask = mask0; N = 3072; words = 48;
      w = bid % 48; int r = bid / 48; i_ch = r % 12; b = r / 12;
    } else {
      int z = bid - 2304;
      sbox = sbox1; mask = mask1; N = 768; words = 12;
      w = z % 12; int r = z / 12; i_ch = r % 3; b = r / 3;
    }
    int i = i_ch * 256 + threadIdx.x;
    if (threadIdx.x < 64)
      bj[threadIdx.x] = ((const float4*)sbox)[(size_t)b * N + w * 64 + threadIdx.x];
    __syncthreads();
    float4 bi = ((const float4*)sbox)[(size_t)b * N + i];
    float ai = (bi.z - bi.x) * (bi.w - bi.y);
    unsigned long long m = 0ull;
#pragma unroll 16
    for (int jj = 0; jj < 64; ++jj) {
      int j = w * 64 + jj;
      float4 bv = bj[jj];
      float lx = fmaxf(bi.x, bv.x), ly = fmaxf(bi.y, bv.y);
      float rx = fminf(bi.z, bv.z), ry = fminf(bi.w, bv.w);
      float iw = fmaxf(rx - lx, 0.f), ih = fmaxf(ry - ly, 0.f);
      float inter = iw * ih;
      float aj = (bv.z - bv.x) * (bv.w - bv.y);
      float iou = inter / (ai + aj - inter);   // NaN compares false, matches jnp
      if ((iou > 0.7f) & (j > i)) m |= (1ull << jj);
    }
    mask[((size_t)b * N + i) * words + w] = m;
  } else {
    __shared__ float4 tb[4][64];
    int sub = threadIdx.x >> 6, lane = threadIdx.x & 63;
    const float* sbox; unsigned long long* colD; int N, tile, b;
    if (bid < 2496) {
      int unit = (bid - 2448) * 4 + sub;
      sbox = sbox0; colD = colD0; N = 3072;
      tile = unit % 48; b = unit / 48;
    } else {
      int unit = (bid - 2496) * 4 + sub;
      sbox = sbox1; colD = colD1; N = 768;
      tile = unit % 12; b = unit / 12;
    }
    tb[sub][lane] = ((const float4*)sbox)[(size_t)b * N + tile * 64 + lane];
    __syncthreads();
    float4 bq = tb[sub][lane];
    float aq = (bq.z - bq.x) * (bq.w - bq.y);
    unsigned long long col = 0ull;
#pragma unroll 16
    for (int ii = 0; ii < 64; ++ii) {
      float4 bi = tb[sub][ii];
      float lx = fmaxf(bq.x, bi.x), ly = fmaxf(bq.y, bi.y);
      float rx = fminf(bq.z, bi.z), ry = fminf(bq.w, bi.w);
      float iw = fmaxf(rx - lx, 0.f), ih = fmaxf(ry - ly, 0.f);
      float inter = iw * ih;
      float ai = (bi.z - bi.x) * (bi.w - bi.y);
      float iou = inter / (aq + ai - inter);
      if ((iou > 0.7f) & (lane > ii)) col |= (1ull << ii);
    }
    colD[(size_t)b * N + tile * 64 + lane] = col;
  }
}

// ---------------- exact greedy scan v3: 4-wave propagation per (b,lvl) ------
__global__ __launch_bounds__(256) void nms_scan_k(
    const float* __restrict__ ssc0, const float* __restrict__ sbox0,
    const unsigned long long* __restrict__ mask0,
    const unsigned long long* __restrict__ colD0,
    const float* __restrict__ ssc1, const float* __restrict__ sbox1,
    const unsigned long long* __restrict__ mask1,
    const unsigned long long* __restrict__ colD1,
    float* __restrict__ cb, float* __restrict__ cs)
{
  int z = blockIdx.x;
  int lvl = z >> 2, b = z & 3;
  int N = lvl ? 768 : 3072;
  int words = lvl ? 12 : 48;
  const float* ssc = (lvl ? ssc1 : ssc0) + (size_t)b * N;
  const float4* sbox = ((const float4*)(lvl ? sbox1 : sbox0)) + (size_t)b * N;
  const unsigned long long* mask = (lvl ? mask1 : mask0) + (size_t)b * N * words;
  const unsigned long long* colD = (lvl ? colD1 : colD0) + (size_t)b * N;
  const int tid = threadIdx.x;
  const int lane = tid & 63;
  const int wv = tid >> 6;
  float* csb = cs + (size_t)b * 2000 + lvl * 1000;
  float4* cbb = (float4*)(cb + ((size_t)b * 2000 + lvl * 1000) * 4);

  __shared__ unsigned long long rem[48];
  __shared__ unsigned long long part[4][64];   // extent 64 (R13 OOB fix)
  __shared__ unsigned long long keepSh;
  __shared__ int doneSh;

  if (tid < 48) rem[tid] = 0ull;
  if (tid == 0) doneSh = 0;
  for (int q = tid; q < 1000; q += 256) {
    csb[q] = -1.f;
    cbb[q] = make_float4(-1.f, -1.f, -1.f, -1.f);
  }
  unsigned long long colv = 0ull; float sc_i = 0.f; float4 bx_i;
  if (wv == 0) { colv = colD[lane]; sc_i = ssc[lane]; bx_i = sbox[lane]; }
  int kept_base = 0;
  __syncthreads();

  for (int t = 0; t < words; ++t) {
    unsigned long long v[16];
    if (lane < words) {
      const unsigned long long* rowb =
          mask + ((size_t)t * 64 + wv * 16) * words + lane;
#pragma unroll
      for (int s = 0; s < 16; ++s) v[s] = rowb[(size_t)s * words];
    }
    if (wv == 0) {
      unsigned long long wr = rem[t];
      bool rm = (wr >> lane) & 1ull;
      bool kp = false;
      unsigned long long Rv = wr;
      unsigned long long Kv = 0ull;
      while (true) {
        bool F = (!rm) && (!kp) && ((colv & ~Rv) == 0ull);
        unsigned long long Fv = __ballot(F);
        if (Fv == 0ull) break;
        kp = kp || F;
        Kv |= Fv;
        bool newr = (!rm) && (!kp) && ((colv & Fv) != 0ull);
        rm = rm || newr;
        Rv = __ballot(rm);
      }
      if (kp) {
        int rank = kept_base + __popcll(Kv & ((1ull << lane) - 1ull));
        if (rank < 1000) { csb[rank] = sc_i; cbb[rank] = bx_i; }
      }
      kept_base += __popcll(Kv);
      if (lane == 0) {
        keepSh = Kv;
        doneSh = (kept_base >= 1000 || t + 1 >= words) ? 1 : 0;
      }
      if (t + 1 < words) {
        int i2 = (t + 1) * 64 + lane;
        colv = colD[i2]; sc_i = ssc[i2]; bx_i = sbox[i2];
      }
    }
    __syncthreads();
    unsigned long long k64 = keepSh;
    int done = doneSh;
    if (lane < words) {
      unsigned long long acc = 0ull;
#pragma unroll
      for (int s = 0; s < 16; ++s)
        acc |= (((k64 >> (wv * 16 + s)) & 1ull) ? v[s] : 0ull);
      part[wv][lane] = acc;
    }
    __syncthreads();
    if (done) break;
    if (tid > t && tid < words)
      rem[tid] |= part[0][tid] | part[1][tid] | part[2][tid] | part[3][tid];
    __syncthreads();
  }
}

// ---------------- final stable descending sort of 2000, gather boxes --------
__global__ __launch_bounds__(256) void final_sort_k(
    const float* __restrict__ cs, const float* __restrict__ cb,
    float* __restrict__ out)
{
  __shared__ __align__(16) float s[2000];
  int b = blockIdx.x >> 3, c = blockIdx.x & 7;
  const float* csb = cs + (size_t)b * 2000;
  for (int j = threadIdx.x; j < 2000; j += 256) s[j] = csb[j];
  __syncthreads();
  if (threadIdx.x >= 250) return;
  int li = c * 250 + threadIdx.x;
  float si = s[li];
  int rank = 0;
  const float4* sv = (const float4*)s;
  for (int j4 = 0; j4 < 500; ++j4) {
    float4 v = sv[j4];
    int j = j4 * 4;
    rank += (v.x > si) || (v.x == si && (j + 0) < li);
    rank += (v.y > si) || (v.y == si && (j + 1) < li);
    rank += (v.z > si) || (v.z == si && (j + 2) < li);
    rank += (v.w > si) || (v.w == si && (j + 3) < li);
  }
  float4 bi = ((const float4*)cb)[(size_t)b * 2000 + li];
  ((float4*)out)[(size_t)b * 2000 + rank] = bi;
}

// ============================================================================
extern "C" void kernel_launch(void* const* d_in, const int* in_sizes, int n_in,
                              void* d_out, int out_size, void* d_ws, size_t ws_size,
                              hipStream_t stream) {
  const float* feat0  = (const float*)d_in[0];
  const float* feat1  = (const float*)d_in[1];
  const float* conv_w = (const float*)d_in[2];
  const float* conv_b = (const float*)d_in[3];
  const float* cls_w  = (const float*)d_in[4];
  const float* cls_b  = (const float*)d_in[5];
  const float* reg_w  = (const float*)d_in[6];
  const float* reg_b  = (const float*)d_in[7];

  char* p = (char*)d_ws;
  auto alloc = [&](size_t bytes) {
    char* r = p;
    p += (bytes + 255) & ~(size_t)255;
    return r;
  };
  double* part0 = (double*)alloc((size_t)4 * 4096 * 256 * 8);    // 33.6 MB
  double* part1 = (double*)alloc((size_t)4 * 1024 * 256 * 8);    //  8.4 MB
  float* box0 = (float*)alloc((size_t)4 * 3072 * 16);
  float* sc0  = (float*)alloc((size_t)4 * 3072 * 4);
  float* box1 = (float*)alloc((size_t)4 * 768 * 16);
  float* sc1  = (float*)alloc((size_t)4 * 768 * 4);
  float* sbox0 = (float*)alloc((size_t)4 * 3072 * 16);
  float* ssc0  = (float*)alloc((size_t)4 * 3072 * 4);
  float* sbox1 = (float*)alloc((size_t)4 * 768 * 16);
  float* ssc1  = (float*)alloc((size_t)4 * 768 * 4);
  unsigned long long* mask0 = (unsigned long long*)alloc((size_t)4 * 3072 * 48 * 8);
  unsigned long long* mask1 = (unsigned long long*)alloc((size_t)4 * 768 * 12 * 8);
  unsigned long long* colD0 = (unsigned long long*)alloc((size_t)4 * 3072 * 8);
  unsigned long long* colD1 = (unsigned long long*)alloc((size_t)4 * 768 * 8);
  float* cb = (float*)alloc((size_t)4 * 2000 * 16);
  float* cs = (float*)alloc((size_t)4 * 2000 * 4);

  conv3_sk_u<<<1280, 256, 0, stream>>>(feat0, feat1, conv_w, part0, part1);
  rhd_k<<<1280, 256, 0, stream>>>(part0, part1, conv_b, cls_w, cls_b,
                                  reg_w, reg_b, box0, sc0, box1, sc1);
  sort_level_k<<<60, 256, 0, stream>>>(sc0, box0, ssc0, sbox0,
                                       sc1, box1, ssc1, sbox1);
  mask_col_k<<<2508, 256, 0, stream>>>(sbox0, sbox1, mask0, mask1, colD0, colD1);
  nms_scan_k<<<8, 256, 0, stream>>>(ssc0, sbox0, mask0, colD0,
                                    ssc1, sbox1, mask1, colD1, cb, cs);
  final_sort_k<<<32, 256, 0, stream>>>(cs, cb, (float*)d_out);
}